// Round 3
// baseline (695.390 us; speedup 1.0000x reference)
//
#include <hip/hip_runtime.h>
#include <hip/hip_bf16.h>

// BronxLayer fused implementation for MI355X (gfx950).  Round 3 (= round 2 + compile fix).
// N=3072 nodes, H=256 hidden, B=4 heads, HD=64 per-head.
//
// Changes vs round 1 (latency-bound k3 at 344us, occupancy 33%):
//  - k3: single barrier/iter (a_s round-trip is wave-private -> no barrier),
//    register-double-buffered eps staging (global latency hidden behind compute),
//    nontemporal eps/diff loads (don't evict kml/hnT from L2),
//    SP 4->8 (1536 blocks, ~20 waves/CU), LDS pad 17 (conflict-free stores).
//  - agg: per-sp private slices (plain stores) when ws_size allows, atomic fallback.
//  - kl: block-reduced, 1 atomic per block.
//  - k0/k1b: LDS-tiled coalesced transposes (were strided scalar gathers).
//  - k35: fused reduce+normalize, vectorized.
// Round-3 fix: __builtin_nontemporal_load needs a native vector type -> use
// ext_vector_type f32x4 instead of HIP_vector_type float4 for eps loads.

#define NN 3072
#define HH 256
#define NB 4
#define HD 64
constexpr int SP = 8;             // z-splits across workgroups
constexpr int ZCHUNK = NN / SP;   // 384
constexpr int ZT = 32;            // z per iteration
constexpr int NIT = ZCHUNK / ZT;  // 12

typedef __attribute__((ext_vector_type(8))) short bf16x8;
typedef __attribute__((ext_vector_type(4))) float f32x4;

static __device__ inline short f2bf(float f) {
    __hip_bfloat16 h = __float2bfloat16(f);
    return __builtin_bit_cast(short, h);
}

// ---------------- k0a: W_k/W_mu/W_ls transpose+permute+convert ----------------
// WTcat[cp][yin], cp = mat*256 + (corig&3)*64 + (corig>>2), value W[yin][corig]
__global__ void k0a_w(const float* __restrict__ Wk, const float* __restrict__ Wmu,
                      const float* __restrict__ Wls, short* __restrict__ WTcat) {
    __shared__ float t[64][65];
    int mat = blockIdx.x >> 4;
    int by = (blockIdx.x >> 2) & 3, bc = blockIdx.x & 3;
    int y0 = by * 64, c0 = bc * 64;
    const float* W = (mat == 0) ? Wk : (mat == 1 ? Wmu : Wls);
    float scale = (mat == 0) ? 0.125f : 1.f;
    int r = threadIdx.x >> 4, c4 = (threadIdx.x & 15) * 4;
#pragma unroll
    for (int i = 0; i < 4; i++) {
        int yl = r + i * 16;
        float4 v = *(const float4*)(W + (y0 + yl) * 256 + c0 + c4);
        t[yl][c4] = v.x; t[yl][c4 + 1] = v.y; t[yl][c4 + 2] = v.z; t[yl][c4 + 3] = v.w;
    }
    __syncthreads();
#pragma unroll
    for (int i = 0; i < 4; i++) {
        int cl = r + i * 16;
        int corig = c0 + cl;
        int cp = mat * 256 + (corig & 3) * 64 + (corig >> 2);
        short4 v = make_short4(f2bf(t[c4][cl] * scale), f2bf(t[c4 + 1][cl] * scale),
                               f2bf(t[c4 + 2][cl] * scale), f2bf(t[c4 + 3][cl] * scale));
        *(short4*)(WTcat + cp * 256 + y0 + c4) = v;
    }
}

// ---------------- k0b: Wv transpose+convert: WvT[n][k] = Wv[k][n] ----------------
__global__ void k0b_wv(const float* __restrict__ Wv, short* __restrict__ WvT) {
    __shared__ float t[64][65];
    int bk = blockIdx.x >> 2, bn = blockIdx.x & 3;
    int k0 = bk * 64, n0 = bn * 64;
    int r = threadIdx.x >> 4, c4 = (threadIdx.x & 15) * 4;
#pragma unroll
    for (int i = 0; i < 4; i++) {
        int kk = r + i * 16;
        float4 v = *(const float4*)(Wv + (k0 + kk) * 256 + n0 + c4);
        t[kk][c4] = v.x; t[kk][c4 + 1] = v.y; t[kk][c4 + 2] = v.z; t[kk][c4 + 3] = v.w;
    }
    __syncthreads();
#pragma unroll
    for (int i = 0; i < 4; i++) {
        int nn = r + i * 16;
        short4 v = make_short4(f2bf(t[c4][nn]), f2bf(t[c4 + 1][nn]),
                               f2bf(t[c4 + 2][nn]), f2bf(t[c4 + 3][nn]));
        *(short4*)(WvT + (n0 + nn) * 1024 + k0 + c4) = v;
    }
}

// ---------------- k0c: bias permute ----------------
__global__ void k0c_bias(const float* __restrict__ bk, const float* __restrict__ bmu,
                         const float* __restrict__ bls, float* __restrict__ biascat) {
    int mat = blockIdx.x, cc = threadIdx.x;
    int corig = (cc & 63) * 4 + (cc >> 6);
    const float* bb = (mat == 0) ? bk : (mat == 1 ? bmu : bls);
    float v = bb[corig];
    if (mat == 0) v *= 0.125f;
    biascat[mat * 256 + cc] = v;
}

// ---------------- k1: LayerNorm ----------------
__global__ void k1_ln(const float* __restrict__ h, const float* __restrict__ gamma,
                      const float* __restrict__ beta, short* __restrict__ hn) {
    int row = blockIdx.x, tid = threadIdx.x;
    float v = h[row * 256 + tid];
    float s = v, s2 = v * v;
    for (int off = 32; off; off >>= 1) {
        s += __shfl_xor(s, off);
        s2 += __shfl_xor(s2, off);
    }
    __shared__ float red[8];
    int w = tid >> 6, lane = tid & 63;
    if (!lane) { red[w] = s; red[4 + w] = s2; }
    __syncthreads();
    s = red[0] + red[1] + red[2] + red[3];
    s2 = red[4] + red[5] + red[6] + red[7];
    float mean = s * (1.f / 256.f);
    float var = s2 * (1.f / 256.f) - mean * mean;
    float rs = rsqrtf(var + 1e-5f);
    hn[row * 256 + tid] = f2bf((v - mean) * rs * gamma[tid] + beta[tid]);
}

// ---------------- k1b: transpose hn -> hnT (LDS-tiled) ----------------
__global__ void k1b_tr(const short* __restrict__ hn, short* __restrict__ hnT) {
    __shared__ short t[64][68];
    int bn = blockIdx.x >> 2, bh = blockIdx.x & 3;
    int n0 = bn * 64, h0 = bh * 64;
    int r = threadIdx.x >> 4, c4 = (threadIdx.x & 15) * 4;
#pragma unroll
    for (int i = 0; i < 4; i++) {
        int nn = r + i * 16;
        *(short4*)&t[nn][c4] = *(const short4*)(hn + (n0 + nn) * 256 + h0 + c4);
    }
    __syncthreads();
#pragma unroll
    for (int i = 0; i < 4; i++) {
        int hh = r + i * 16;
        short4 v = make_short4(t[c4][hh], t[c4 + 1][hh], t[c4 + 2][hh], t[c4 + 3][hh]);
        *(short4*)(hnT + (h0 + hh) * NN + n0 + c4) = v;
    }
}

// ---------------- k2: projections (bf16 MFMA) ----------------
__global__ __launch_bounds__(256) void k2_proj(const short* __restrict__ hn,
                                               const short* __restrict__ WTcat,
                                               const float* __restrict__ biascat,
                                               short* __restrict__ kml) {
    int bx = blockIdx.x;
    int mt = bx / 12, nb = bx % 12;
    int m0 = mt * 64, n0 = nb * 64;
    int tid = threadIdx.x, w = tid >> 6, lane = tid & 63, q = lane >> 4, c = lane & 15;
    int mrow = m0 + w * 16;
    f32x4 acc[4] = {{0, 0, 0, 0}, {0, 0, 0, 0}, {0, 0, 0, 0}, {0, 0, 0, 0}};
    for (int k0 = 0; k0 < 256; k0 += 32) {
        bf16x8 af = *(const bf16x8*)(hn + (mrow + c) * 256 + k0 + q * 8);
#pragma unroll
        for (int nt = 0; nt < 4; nt++) {
            bf16x8 bf = *(const bf16x8*)(WTcat + (n0 + nt * 16 + c) * 256 + k0 + q * 8);
            acc[nt] = __builtin_amdgcn_mfma_f32_16x16x32_bf16(af, bf, acc[nt], 0, 0, 0);
        }
    }
#pragma unroll
    for (int nt = 0; nt < 4; nt++) {
        int cp = n0 + nt * 16 + c;
        float bias = biascat[cp];
        int mat = cp >> 8, b = (cp >> 6) & 3, y = cp & 63;
        short* dst = kml + (mat * 4 + b) * (NN * HD);
#pragma unroll
        for (int r = 0; r < 4; r++) {
            int m = mrow + 4 * q + r;
            dst[m * HD + y] = f2bf(acc[nt][r] + bias);
        }
    }
}

// ---------------- k3: fused attention-like core (pipelined) ----------------
__global__ __launch_bounds__(256, 5) void k3_fused(
    const short* __restrict__ kh, const short* __restrict__ muh,
    const short* __restrict__ lsh, const short* __restrict__ hnT,
    const float* __restrict__ eps, const float* __restrict__ diff,
    float* __restrict__ aggout, float* __restrict__ denom, float* __restrict__ klsum,
    int use_partial) {
    __shared__ float eps_s[2][4][32][17];  // pad 17: stores conflict-free
    __shared__ float diff_s[2][32][17];
    __shared__ short a_s[4][16][40];       // wave-private; pad 40 keeps b128 aligned
    __shared__ float klred[4];

    const int tid = threadIdx.x;
    const int w = tid >> 6;     // wave == head
    const int lane = tid & 63;
    const int q = lane >> 4;
    const int c = lane & 15;

    const int xt = blockIdx.x >> 3;   // SP==8
    const int sp = blockIdx.x & 7;
    const int x0 = xt * 16;
    const int zbase = sp * ZCHUNK;

    // Q (kh, pre-scaled) fragments: B-operand of S^T
    const bf16x8 qf0 = *(const bf16x8*)(kh + (w * NN + x0 + c) * HD + q * 8);
    const bf16x8 qf1 = *(const bf16x8*)(kh + (w * NN + x0 + c) * HD + 32 + q * 8);

    f32x4 acc[16];
#pragma unroll
    for (int i = 0; i < 16; i++) acc[i] = (f32x4){0.f, 0.f, 0.f, 0.f};
    float den_acc = 0.f, kl_acc = 0.f;

    int xx[2], zz[2];
#pragma unroll
    for (int i = 0; i < 2; i++) { int p = i * 256 + tid; xx[i] = p >> 5; zz[i] = p & 31; }

    // prologue: stage it=0 into buffer 0
    f32x4 e_reg[2];
    float d_reg[2];
#pragma unroll
    for (int i = 0; i < 2; i++) {
        int base = (x0 + xx[i]) * NN + zbase + zz[i];
        e_reg[i] = __builtin_nontemporal_load((const f32x4*)(eps + (size_t)base * 4));
        d_reg[i] = __builtin_nontemporal_load(diff + base);
    }
#pragma unroll
    for (int i = 0; i < 2; i++) {
        eps_s[0][0][zz[i]][xx[i]] = e_reg[i].x;
        eps_s[0][1][zz[i]][xx[i]] = e_reg[i].y;
        eps_s[0][2][zz[i]][xx[i]] = e_reg[i].z;
        eps_s[0][3][zz[i]][xx[i]] = e_reg[i].w;
        diff_s[0][zz[i]][xx[i]] = d_reg[i];
    }
    __syncthreads();

    for (int it = 0; it < NIT; ++it) {
        const int cur = it & 1, nxt = cur ^ 1;
        const int z0 = zbase + it * ZT;

        // issue next-iter eps loads early (drained after compute, before stores)
        if (it + 1 < NIT) {
#pragma unroll
            for (int i = 0; i < 2; i++) {
                int base = (x0 + xx[i]) * NN + z0 + ZT + zz[i];
                e_reg[i] = __builtin_nontemporal_load((const f32x4*)(eps + (size_t)base * 4));
                d_reg[i] = __builtin_nontemporal_load(diff + base);
            }
        }

        // S^T = muh/lsh @ kh^T for this head: D[m=z][n=x], two 16-z subtiles
        const short* muw = muh + (size_t)(w * NN + z0) * HD;
        const short* lsw = lsh + (size_t)(w * NN + z0) * HD;
        f32x4 smu[2], sls[2];
#pragma unroll
        for (int t = 0; t < 2; t++) {
            bf16x8 a0 = *(const bf16x8*)(muw + (t * 16 + c) * HD + q * 8);
            bf16x8 a1 = *(const bf16x8*)(muw + (t * 16 + c) * HD + 32 + q * 8);
            f32x4 z4 = (f32x4){0.f, 0.f, 0.f, 0.f};
            z4 = __builtin_amdgcn_mfma_f32_16x16x32_bf16(a0, qf0, z4, 0, 0, 0);
            z4 = __builtin_amdgcn_mfma_f32_16x16x32_bf16(a1, qf1, z4, 0, 0, 0);
            smu[t] = z4;
            bf16x8 b0 = *(const bf16x8*)(lsw + (t * 16 + c) * HD + q * 8);
            bf16x8 b1 = *(const bf16x8*)(lsw + (t * 16 + c) * HD + 32 + q * 8);
            f32x4 y4 = (f32x4){0.f, 0.f, 0.f, 0.f};
            y4 = __builtin_amdgcn_mfma_f32_16x16x32_bf16(b0, qf0, y4, 0, 0, 0);
            y4 = __builtin_amdgcn_mfma_f32_16x16x32_bf16(b1, qf1, y4, 0, 0, 0);
            sls[t] = y4;
        }

        // elementwise: x = x0 + c, z = z0 + 16t + 4q + r
#pragma unroll
        for (int t = 0; t < 2; t++) {
            short pk[4];
#pragma unroll
            for (int r = 0; r < 4; r++) {
                int zl = t * 16 + 4 * q + r;
                float mu = smu[t][r];
                float ls = sls[t][r];
                float e = eps_s[cur][w][zl][c];
                float d = diff_s[cur][zl][c];
                float ex = __expf(-fabsf(ls));
                float sg = fmaxf(ls, 0.f) + __logf(1.f + ex);
                float kle = -__logf(sg) + 0.5f * (sg * sg + mu * mu) - 0.5f;
                float sgn = (d > 0.f) ? 1.f : ((d < 0.f) ? -1.f : 0.f);
                kl_acc += sgn * kle;
                float a = __expf(mu + sg * e) * d;
                den_acc += fabsf(a);
                pk[r] = f2bf(a);
            }
            *reinterpret_cast<short4*>(&a_s[w][c][t * 16 + 4 * q]) =
                make_short4(pk[0], pk[1], pk[2], pk[3]);
        }
        // a_s is wave-private (indexed by w); same-wave DS ops complete in order,
        // so no barrier needed between the write above and the read below.
        bf16x8 af = *(const bf16x8*)(&a_s[w][c][q * 8]);
#pragma unroll
        for (int nt = 0; nt < 16; nt++) {
            bf16x8 bf = *(const bf16x8*)(hnT + (size_t)(nt * 16 + c) * NN + z0 + q * 8);
            acc[nt] = __builtin_amdgcn_mfma_f32_16x16x32_bf16(af, bf, acc[nt], 0, 0, 0);
        }

        // store staged next-iter eps (vmcnt drain lands here, after compute)
        if (it + 1 < NIT) {
#pragma unroll
            for (int i = 0; i < 2; i++) {
                eps_s[nxt][0][zz[i]][xx[i]] = e_reg[i].x;
                eps_s[nxt][1][zz[i]][xx[i]] = e_reg[i].y;
                eps_s[nxt][2][zz[i]][xx[i]] = e_reg[i].z;
                eps_s[nxt][3][zz[i]][xx[i]] = e_reg[i].w;
                diff_s[nxt][zz[i]][xx[i]] = d_reg[i];
            }
        }
        __syncthreads();
    }

    // denominator: lane's elements all at x = x0 + c; reduce across quads
    den_acc += __shfl_down(den_acc, 32);
    den_acc += __shfl_down(den_acc, 16);
    if (q == 0) atomicAdd(&denom[(x0 + c) * NB + w], den_acc);
    // kl: wave reduce, then block reduce, 1 atomic per block
    for (int off = 32; off; off >>= 1) kl_acc += __shfl_xor(kl_acc, off);
    if (lane == 0) klred[w] = kl_acc;
    __syncthreads();
    if (tid == 0) atomicAdd(klsum, klred[0] + klred[1] + klred[2] + klred[3]);

    // agg: C-layout row = 4q+r -> x, col = c -> h
    if (use_partial) {
        float* dst = aggout + (size_t)sp * (NN * NB * HH);
#pragma unroll
        for (int nt = 0; nt < 16; nt++)
#pragma unroll
            for (int r = 0; r < 4; r++)
                dst[((size_t)(x0 + 4 * q + r) * NB + w) * HH + nt * 16 + c] = acc[nt][r];
    } else {
#pragma unroll
        for (int nt = 0; nt < 16; nt++)
#pragma unroll
            for (int r = 0; r < 4; r++)
                atomicAdd(&aggout[((size_t)(x0 + 4 * q + r) * NB + w) * HH + nt * 16 + c],
                          acc[nt][r]);
    }
}

// ---------------- k35: reduce partials + normalize -> bf16 ----------------
__global__ void k35_norm(const float* __restrict__ aggp, int nsl,
                         const float* __restrict__ denom, short* __restrict__ aggn) {
    int x = blockIdx.x, tid = threadIdx.x;
    int b = tid >> 6;
    int h4 = (tid & 63) * 4;
    size_t base = ((size_t)x * 4 + b) * 256 + h4;
    float4 s = {0.f, 0.f, 0.f, 0.f};
    for (int sp = 0; sp < nsl; sp++) {
        float4 v = *(const float4*)(aggp + (size_t)sp * (NN * 4 * 256) + base);
        s.x += v.x; s.y += v.y; s.z += v.z; s.w += v.w;
    }
    float r = 1.f / fmaxf(denom[x * 4 + b], 1e-12f);
    short4 o = make_short4(f2bf(s.x * r), f2bf(s.y * r), f2bf(s.z * r), f2bf(s.w * r));
    *(short4*)(aggn + base) = o;
}

// ---------------- k4: fc_v + elu + residual + kl ----------------
__global__ __launch_bounds__(256) void k4_out(const short* __restrict__ aggn,
                                              const short* __restrict__ WvT,
                                              const float* __restrict__ bv,
                                              const float* __restrict__ h,
                                              const float* __restrict__ klsum,
                                              float* __restrict__ out) {
    int bx = blockIdx.x;
    int mt = bx >> 2, nb = bx & 3;
    int m0 = mt * 64, n0 = nb * 64;
    int tid = threadIdx.x, w = tid >> 6, lane = tid & 63, q = lane >> 4, c = lane & 15;
    int mrow = m0 + w * 16;
    f32x4 acc[4] = {{0, 0, 0, 0}, {0, 0, 0, 0}, {0, 0, 0, 0}, {0, 0, 0, 0}};
    for (int k0 = 0; k0 < 1024; k0 += 32) {
        bf16x8 af = *(const bf16x8*)(aggn + (mrow + c) * 1024 + k0 + q * 8);
#pragma unroll
        for (int nt = 0; nt < 4; nt++) {
            bf16x8 bf = *(const bf16x8*)(WvT + (n0 + nt * 16 + c) * 1024 + k0 + q * 8);
            acc[nt] = __builtin_amdgcn_mfma_f32_16x16x32_bf16(af, bf, acc[nt], 0, 0, 0);
        }
    }
#pragma unroll
    for (int nt = 0; nt < 4; nt++) {
        int col = n0 + nt * 16 + c;
        float bias = bv[col];
#pragma unroll
        for (int r = 0; r < 4; r++) {
            int row = mrow + 4 * q + r;
            float v = acc[nt][r] + bias;
            v = (v > 0.f) ? v : (__expf(v) - 1.f);  // elu
            out[row * 256 + col] = v + h[row * 256 + col];
        }
    }
    if (bx == 0 && tid == 0) out[786432] = klsum[0] * (1.0f / 9437184.0f);
}

extern "C" void kernel_launch(void* const* d_in, const int* in_sizes, int n_in,
                              void* d_out, int out_size, void* d_ws, size_t ws_size,
                              hipStream_t stream) {
    const float* h = (const float*)d_in[0];
    const float* gamma = (const float*)d_in[1];
    const float* beta = (const float*)d_in[2];
    const float* Wk = (const float*)d_in[3];
    const float* bk = (const float*)d_in[4];
    const float* Wmu = (const float*)d_in[5];
    const float* bmu = (const float*)d_in[6];
    const float* Wls = (const float*)d_in[7];
    const float* bls = (const float*)d_in[8];
    const float* Wv = (const float*)d_in[9];
    const float* bv = (const float*)d_in[10];
    const float* diff = (const float*)d_in[11];
    const float* eps = (const float*)d_in[12];
    float* out = (float*)d_out;

    const size_t slice = (size_t)NN * NB * HH * 4;  // 12,582,912 B
    const size_t fixed = 49152 + 4096 + 1572864 + 1572864 + 4718592 + 393216 + 4096 +
                         524288 + 6291456;          // ~15.1 MB
    int use_partial = (ws_size >= (size_t)SP * slice + fixed) ? 1 : 0;
    size_t agg_bytes = use_partial ? (size_t)SP * slice : slice;

    char* p = (char*)d_ws;
    float* aggbuf = (float*)p; p += agg_bytes;
    float* denom = (float*)p;  p += 49152;
    float* klsum = (float*)p;  p += 4096;
    short* hn = (short*)p;     p += 1572864;
    short* hnT = (short*)p;    p += 1572864;
    short* kml = (short*)p;    p += 4718592;
    short* WTcat = (short*)p;  p += 393216;
    float* biasc = (float*)p;  p += 4096;
    short* WvT = (short*)p;    p += 524288;
    short* aggn = (short*)p;

    if (use_partial) {
        (void)hipMemsetAsync(denom, 0, 49152 + 4096, stream);        // denom + klsum
    } else {
        (void)hipMemsetAsync(aggbuf, 0, slice + 49152 + 4096, stream);  // agg+denom+klsum
    }

    k0a_w<<<48, 256, 0, stream>>>(Wk, Wmu, Wls, WTcat);
    k0b_wv<<<64, 256, 0, stream>>>(Wv, WvT);
    k0c_bias<<<3, 256, 0, stream>>>(bk, bmu, bls, biasc);
    k1_ln<<<3072, 256, 0, stream>>>(h, gamma, beta, hn);
    k1b_tr<<<192, 256, 0, stream>>>(hn, hnT);
    k2_proj<<<576, 256, 0, stream>>>(hn, WTcat, biasc, kml);
    k3_fused<<<NN / 16 * SP, 256, 0, stream>>>(kml, kml + 4 * NN * HD, kml + 8 * NN * HD,
                                               hnT, eps, diff, aggbuf, denom, klsum,
                                               use_partial);
    k35_norm<<<3072, 256, 0, stream>>>(aggbuf, use_partial ? SP : 1, denom, aggn);
    k4_out<<<192, 256, 0, stream>>>(aggn, WvT, bv, h, klsum, out);
}

// Round 4
// 546.040 us; speedup vs baseline: 1.2735x; 1.2735x over previous
//
#include <hip/hip_runtime.h>
#include <hip/hip_bf16.h>

// BronxLayer fused implementation for MI355X (gfx950).  Round 4.
// N=3072 nodes, H=256 hidden, B=4 heads, HD=64 per-head.
//
// Round-4 changes (r3 spilled: launch_bounds(256,5) forced 48 VGPRs < 64-reg
// accumulator -> ~380MB/way scratch traffic, 476us):
//  - k3: plain __launch_bounds__(256): let acc live in AGPRs, no spill.
//  - k3: agg via atomicAdd (r1-style; L2 absorbs, ~50MB HBM write) instead of
//    8x12.6MB partial slices + 100MB readback.
//  - merged k0a/k0b/k0c into one dispatch (fewer graph nodes).
//  - keep: SP=8 grid 1536 (~6 blocks/CU avail), single barrier/iter,
//    register-double-buffered nontemporal eps/diff prefetch.

#define NN 3072
#define HH 256
#define NB 4
#define HD 64
constexpr int SP = 8;             // z-splits across workgroups
constexpr int ZCHUNK = NN / SP;   // 384
constexpr int ZT = 32;            // z per iteration
constexpr int NIT = ZCHUNK / ZT;  // 12

typedef __attribute__((ext_vector_type(8))) short bf16x8;
typedef __attribute__((ext_vector_type(4))) float f32x4;

static __device__ inline short f2bf(float f) {
    __hip_bfloat16 h = __float2bfloat16(f);
    return __builtin_bit_cast(short, h);
}

// ---------------- k0: all weight prep in one dispatch ----------------
// blocks 0..47   : WTcat[cp][yin], cp = mat*256 + (corig&3)*64 + (corig>>2)
// blocks 48..111 : WvT[n][k] = Wv[k][n]
// block  112     : bias permute
__global__ void k0_prep(const float* __restrict__ Wk, const float* __restrict__ Wmu,
                        const float* __restrict__ Wls, const float* __restrict__ bk,
                        const float* __restrict__ bmu, const float* __restrict__ bls,
                        const float* __restrict__ Wv, short* __restrict__ WTcat,
                        float* __restrict__ biascat, short* __restrict__ WvT) {
    __shared__ float t[64][65];
    int bx = blockIdx.x;
    if (bx < 48) {
        int mat = bx >> 4;
        int by = (bx >> 2) & 3, bc = bx & 3;
        int y0 = by * 64, c0 = bc * 64;
        const float* W = (mat == 0) ? Wk : (mat == 1 ? Wmu : Wls);
        float scale = (mat == 0) ? 0.125f : 1.f;
        int r = threadIdx.x >> 4, c4 = (threadIdx.x & 15) * 4;
#pragma unroll
        for (int i = 0; i < 4; i++) {
            int yl = r + i * 16;
            float4 v = *(const float4*)(W + (y0 + yl) * 256 + c0 + c4);
            t[yl][c4] = v.x; t[yl][c4 + 1] = v.y; t[yl][c4 + 2] = v.z; t[yl][c4 + 3] = v.w;
        }
        __syncthreads();
#pragma unroll
        for (int i = 0; i < 4; i++) {
            int cl = r + i * 16;
            int corig = c0 + cl;
            int cp = mat * 256 + (corig & 3) * 64 + (corig >> 2);
            short4 v = make_short4(f2bf(t[c4][cl] * scale), f2bf(t[c4 + 1][cl] * scale),
                                   f2bf(t[c4 + 2][cl] * scale), f2bf(t[c4 + 3][cl] * scale));
            *(short4*)(WTcat + cp * 256 + y0 + c4) = v;
        }
        return;
    }
    if (bx < 112) {
        int b = bx - 48;
        int bk2 = b >> 2, bn = b & 3;
        int k0 = bk2 * 64, n0 = bn * 64;
        int r = threadIdx.x >> 4, c4 = (threadIdx.x & 15) * 4;
#pragma unroll
        for (int i = 0; i < 4; i++) {
            int kk = r + i * 16;
            float4 v = *(const float4*)(Wv + (k0 + kk) * 256 + n0 + c4);
            t[kk][c4] = v.x; t[kk][c4 + 1] = v.y; t[kk][c4 + 2] = v.z; t[kk][c4 + 3] = v.w;
        }
        __syncthreads();
#pragma unroll
        for (int i = 0; i < 4; i++) {
            int nn = r + i * 16;
            short4 v = make_short4(f2bf(t[c4][nn]), f2bf(t[c4 + 1][nn]),
                                   f2bf(t[c4 + 2][nn]), f2bf(t[c4 + 3][nn]));
            *(short4*)(WvT + (n0 + nn) * 1024 + k0 + c4) = v;
        }
        return;
    }
    // bias permute: 3 mats x 256
    int cc = threadIdx.x;
    int corig = (cc & 63) * 4 + (cc >> 6);
    biascat[cc] = bk[corig] * 0.125f;
    biascat[256 + cc] = bmu[corig];
    biascat[512 + cc] = bls[corig];
}

// ---------------- k1: LayerNorm ----------------
__global__ void k1_ln(const float* __restrict__ h, const float* __restrict__ gamma,
                      const float* __restrict__ beta, short* __restrict__ hn) {
    int row = blockIdx.x, tid = threadIdx.x;
    float v = h[row * 256 + tid];
    float s = v, s2 = v * v;
    for (int off = 32; off; off >>= 1) {
        s += __shfl_xor(s, off);
        s2 += __shfl_xor(s2, off);
    }
    __shared__ float red[8];
    int w = tid >> 6, lane = tid & 63;
    if (!lane) { red[w] = s; red[4 + w] = s2; }
    __syncthreads();
    s = red[0] + red[1] + red[2] + red[3];
    s2 = red[4] + red[5] + red[6] + red[7];
    float mean = s * (1.f / 256.f);
    float var = s2 * (1.f / 256.f) - mean * mean;
    float rs = rsqrtf(var + 1e-5f);
    hn[row * 256 + tid] = f2bf((v - mean) * rs * gamma[tid] + beta[tid]);
}

// ---------------- k1b: transpose hn -> hnT (LDS-tiled) ----------------
__global__ void k1b_tr(const short* __restrict__ hn, short* __restrict__ hnT) {
    __shared__ short t[64][68];
    int bn = blockIdx.x >> 2, bh = blockIdx.x & 3;
    int n0 = bn * 64, h0 = bh * 64;
    int r = threadIdx.x >> 4, c4 = (threadIdx.x & 15) * 4;
#pragma unroll
    for (int i = 0; i < 4; i++) {
        int nn = r + i * 16;
        *(short4*)&t[nn][c4] = *(const short4*)(hn + (n0 + nn) * 256 + h0 + c4);
    }
    __syncthreads();
#pragma unroll
    for (int i = 0; i < 4; i++) {
        int hh = r + i * 16;
        short4 v = make_short4(t[c4][hh], t[c4 + 1][hh], t[c4 + 2][hh], t[c4 + 3][hh]);
        *(short4*)(hnT + (h0 + hh) * NN + n0 + c4) = v;
    }
}

// ---------------- k2: projections (bf16 MFMA) ----------------
__global__ __launch_bounds__(256) void k2_proj(const short* __restrict__ hn,
                                               const short* __restrict__ WTcat,
                                               const float* __restrict__ biascat,
                                               short* __restrict__ kml) {
    int bx = blockIdx.x;
    int mt = bx / 12, nb = bx % 12;
    int m0 = mt * 64, n0 = nb * 64;
    int tid = threadIdx.x, w = tid >> 6, lane = tid & 63, q = lane >> 4, c = lane & 15;
    int mrow = m0 + w * 16;
    f32x4 acc[4] = {{0, 0, 0, 0}, {0, 0, 0, 0}, {0, 0, 0, 0}, {0, 0, 0, 0}};
    for (int k0 = 0; k0 < 256; k0 += 32) {
        bf16x8 af = *(const bf16x8*)(hn + (mrow + c) * 256 + k0 + q * 8);
#pragma unroll
        for (int nt = 0; nt < 4; nt++) {
            bf16x8 bf = *(const bf16x8*)(WTcat + (n0 + nt * 16 + c) * 256 + k0 + q * 8);
            acc[nt] = __builtin_amdgcn_mfma_f32_16x16x32_bf16(af, bf, acc[nt], 0, 0, 0);
        }
    }
#pragma unroll
    for (int nt = 0; nt < 4; nt++) {
        int cp = n0 + nt * 16 + c;
        float bias = biascat[cp];
        int mat = cp >> 8, b = (cp >> 6) & 3, y = cp & 63;
        short* dst = kml + (mat * 4 + b) * (NN * HD);
#pragma unroll
        for (int r = 0; r < 4; r++) {
            int m = mrow + 4 * q + r;
            dst[m * HD + y] = f2bf(acc[nt][r] + bias);
        }
    }
}

// ---------------- k3: fused attention-like core (pipelined, no spill) ----------------
__global__ __launch_bounds__(256) void k3_fused(
    const short* __restrict__ kh, const short* __restrict__ muh,
    const short* __restrict__ lsh, const short* __restrict__ hnT,
    const float* __restrict__ eps, const float* __restrict__ diff,
    float* __restrict__ agg, float* __restrict__ denom, float* __restrict__ klsum) {
    __shared__ float eps_s[2][4][32][17];  // pad 17: stores conflict-free
    __shared__ float diff_s[2][32][17];
    __shared__ short a_s[4][16][40];       // wave-private; pad 40 keeps b128 aligned
    __shared__ float klred[4];

    const int tid = threadIdx.x;
    const int w = tid >> 6;     // wave == head
    const int lane = tid & 63;
    const int q = lane >> 4;
    const int c = lane & 15;

    const int xt = blockIdx.x >> 3;   // SP==8
    const int sp = blockIdx.x & 7;
    const int x0 = xt * 16;
    const int zbase = sp * ZCHUNK;

    // Q (kh, pre-scaled) fragments: B-operand of S^T
    const bf16x8 qf0 = *(const bf16x8*)(kh + (w * NN + x0 + c) * HD + q * 8);
    const bf16x8 qf1 = *(const bf16x8*)(kh + (w * NN + x0 + c) * HD + 32 + q * 8);

    f32x4 acc[16];
#pragma unroll
    for (int i = 0; i < 16; i++) acc[i] = (f32x4){0.f, 0.f, 0.f, 0.f};
    float den_acc = 0.f, kl_acc = 0.f;

    int xx[2], zz[2];
#pragma unroll
    for (int i = 0; i < 2; i++) { int p = i * 256 + tid; xx[i] = p >> 5; zz[i] = p & 31; }

    // prologue: stage it=0 into buffer 0
    f32x4 e_reg[2];
    float d_reg[2];
#pragma unroll
    for (int i = 0; i < 2; i++) {
        int base = (x0 + xx[i]) * NN + zbase + zz[i];
        e_reg[i] = __builtin_nontemporal_load((const f32x4*)(eps + (size_t)base * 4));
        d_reg[i] = __builtin_nontemporal_load(diff + base);
    }
#pragma unroll
    for (int i = 0; i < 2; i++) {
        eps_s[0][0][zz[i]][xx[i]] = e_reg[i].x;
        eps_s[0][1][zz[i]][xx[i]] = e_reg[i].y;
        eps_s[0][2][zz[i]][xx[i]] = e_reg[i].z;
        eps_s[0][3][zz[i]][xx[i]] = e_reg[i].w;
        diff_s[0][zz[i]][xx[i]] = d_reg[i];
    }
    __syncthreads();

    for (int it = 0; it < NIT; ++it) {
        const int cur = it & 1, nxt = cur ^ 1;
        const int z0 = zbase + it * ZT;

        // issue next-iter eps loads early (drained after compute, before stores)
        if (it + 1 < NIT) {
#pragma unroll
            for (int i = 0; i < 2; i++) {
                int base = (x0 + xx[i]) * NN + z0 + ZT + zz[i];
                e_reg[i] = __builtin_nontemporal_load((const f32x4*)(eps + (size_t)base * 4));
                d_reg[i] = __builtin_nontemporal_load(diff + base);
            }
        }

        // S^T = muh/lsh @ kh^T for this head: D[m=z][n=x], two 16-z subtiles
        const short* muw = muh + (size_t)(w * NN + z0) * HD;
        const short* lsw = lsh + (size_t)(w * NN + z0) * HD;
        f32x4 smu[2], sls[2];
#pragma unroll
        for (int t = 0; t < 2; t++) {
            bf16x8 a0 = *(const bf16x8*)(muw + (t * 16 + c) * HD + q * 8);
            bf16x8 a1 = *(const bf16x8*)(muw + (t * 16 + c) * HD + 32 + q * 8);
            f32x4 z4 = (f32x4){0.f, 0.f, 0.f, 0.f};
            z4 = __builtin_amdgcn_mfma_f32_16x16x32_bf16(a0, qf0, z4, 0, 0, 0);
            z4 = __builtin_amdgcn_mfma_f32_16x16x32_bf16(a1, qf1, z4, 0, 0, 0);
            smu[t] = z4;
            bf16x8 b0 = *(const bf16x8*)(lsw + (t * 16 + c) * HD + q * 8);
            bf16x8 b1 = *(const bf16x8*)(lsw + (t * 16 + c) * HD + 32 + q * 8);
            f32x4 y4 = (f32x4){0.f, 0.f, 0.f, 0.f};
            y4 = __builtin_amdgcn_mfma_f32_16x16x32_bf16(b0, qf0, y4, 0, 0, 0);
            y4 = __builtin_amdgcn_mfma_f32_16x16x32_bf16(b1, qf1, y4, 0, 0, 0);
            sls[t] = y4;
        }

        // elementwise: x = x0 + c, z = z0 + 16t + 4q + r
#pragma unroll
        for (int t = 0; t < 2; t++) {
            short pk[4];
#pragma unroll
            for (int r = 0; r < 4; r++) {
                int zl = t * 16 + 4 * q + r;
                float mu = smu[t][r];
                float ls = sls[t][r];
                float e = eps_s[cur][w][zl][c];
                float d = diff_s[cur][zl][c];
                float ex = __expf(-fabsf(ls));
                float sg = fmaxf(ls, 0.f) + __logf(1.f + ex);
                float kle = -__logf(sg) + 0.5f * (sg * sg + mu * mu) - 0.5f;
                float sgn = (d > 0.f) ? 1.f : ((d < 0.f) ? -1.f : 0.f);
                kl_acc += sgn * kle;
                float a = __expf(mu + sg * e) * d;
                den_acc += fabsf(a);
                pk[r] = f2bf(a);
            }
            *reinterpret_cast<short4*>(&a_s[w][c][t * 16 + 4 * q]) =
                make_short4(pk[0], pk[1], pk[2], pk[3]);
        }
        // a_s is wave-private (indexed by w); same-wave DS ops complete in order,
        // so no barrier needed between the write above and the read below.
        bf16x8 af = *(const bf16x8*)(&a_s[w][c][q * 8]);
#pragma unroll
        for (int nt = 0; nt < 16; nt++) {
            bf16x8 bf = *(const bf16x8*)(hnT + (size_t)(nt * 16 + c) * NN + z0 + q * 8);
            acc[nt] = __builtin_amdgcn_mfma_f32_16x16x32_bf16(af, bf, acc[nt], 0, 0, 0);
        }

        // store staged next-iter eps (vmcnt drain lands here, after compute)
        if (it + 1 < NIT) {
#pragma unroll
            for (int i = 0; i < 2; i++) {
                eps_s[nxt][0][zz[i]][xx[i]] = e_reg[i].x;
                eps_s[nxt][1][zz[i]][xx[i]] = e_reg[i].y;
                eps_s[nxt][2][zz[i]][xx[i]] = e_reg[i].z;
                eps_s[nxt][3][zz[i]][xx[i]] = e_reg[i].w;
                diff_s[nxt][zz[i]][xx[i]] = d_reg[i];
            }
        }
        __syncthreads();
    }

    // denominator: lane's elements all at x = x0 + c; reduce across quads
    den_acc += __shfl_down(den_acc, 32);
    den_acc += __shfl_down(den_acc, 16);
    if (q == 0) atomicAdd(&denom[(x0 + c) * NB + w], den_acc);
    // kl: wave reduce, then block reduce, 1 atomic per block
    for (int off = 32; off; off >>= 1) kl_acc += __shfl_xor(kl_acc, off);
    if (lane == 0) klred[w] = kl_acc;
    __syncthreads();
    if (tid == 0) atomicAdd(klsum, klred[0] + klred[1] + klred[2] + klred[3]);

    // agg: C-layout row = 4q+r -> x, col = c -> h; atomics (L2-absorbed)
#pragma unroll
    for (int nt = 0; nt < 16; nt++)
#pragma unroll
        for (int r = 0; r < 4; r++)
            atomicAdd(&agg[((size_t)(x0 + 4 * q + r) * NB + w) * HH + nt * 16 + c],
                      acc[nt][r]);
}

// ---------------- k35: normalize -> bf16 ----------------
__global__ void k35_norm(const float* __restrict__ agg, const float* __restrict__ denom,
                         short* __restrict__ aggn) {
    int x = blockIdx.x, tid = threadIdx.x;
    int b = tid >> 6;
    int h4 = (tid & 63) * 4;
    size_t base = ((size_t)x * 4 + b) * 256 + h4;
    float4 s = *(const float4*)(agg + base);
    float r = 1.f / fmaxf(denom[x * 4 + b], 1e-12f);
    short4 o = make_short4(f2bf(s.x * r), f2bf(s.y * r), f2bf(s.z * r), f2bf(s.w * r));
    *(short4*)(aggn + base) = o;
}

// ---------------- k4: fc_v + elu + residual + kl ----------------
__global__ __launch_bounds__(256) void k4_out(const short* __restrict__ aggn,
                                              const short* __restrict__ WvT,
                                              const float* __restrict__ bv,
                                              const float* __restrict__ h,
                                              const float* __restrict__ klsum,
                                              float* __restrict__ out) {
    int bx = blockIdx.x;
    int mt = bx >> 2, nb = bx & 3;
    int m0 = mt * 64, n0 = nb * 64;
    int tid = threadIdx.x, w = tid >> 6, lane = tid & 63, q = lane >> 4, c = lane & 15;
    int mrow = m0 + w * 16;
    f32x4 acc[4] = {{0, 0, 0, 0}, {0, 0, 0, 0}, {0, 0, 0, 0}, {0, 0, 0, 0}};
    for (int k0 = 0; k0 < 1024; k0 += 32) {
        bf16x8 af = *(const bf16x8*)(aggn + (mrow + c) * 1024 + k0 + q * 8);
#pragma unroll
        for (int nt = 0; nt < 4; nt++) {
            bf16x8 bf = *(const bf16x8*)(WvT + (n0 + nt * 16 + c) * 1024 + k0 + q * 8);
            acc[nt] = __builtin_amdgcn_mfma_f32_16x16x32_bf16(af, bf, acc[nt], 0, 0, 0);
        }
    }
#pragma unroll
    for (int nt = 0; nt < 4; nt++) {
        int col = n0 + nt * 16 + c;
        float bias = bv[col];
#pragma unroll
        for (int r = 0; r < 4; r++) {
            int row = mrow + 4 * q + r;
            float v = acc[nt][r] + bias;
            v = (v > 0.f) ? v : (__expf(v) - 1.f);  // elu
            out[row * 256 + col] = v + h[row * 256 + col];
        }
    }
    if (bx == 0 && tid == 0) out[786432] = klsum[0] * (1.0f / 9437184.0f);
}

extern "C" void kernel_launch(void* const* d_in, const int* in_sizes, int n_in,
                              void* d_out, int out_size, void* d_ws, size_t ws_size,
                              hipStream_t stream) {
    const float* h = (const float*)d_in[0];
    const float* gamma = (const float*)d_in[1];
    const float* beta = (const float*)d_in[2];
    const float* Wk = (const float*)d_in[3];
    const float* bk = (const float*)d_in[4];
    const float* Wmu = (const float*)d_in[5];
    const float* bmu = (const float*)d_in[6];
    const float* Wls = (const float*)d_in[7];
    const float* bls = (const float*)d_in[8];
    const float* Wv = (const float*)d_in[9];
    const float* bv = (const float*)d_in[10];
    const float* diff = (const float*)d_in[11];
    const float* eps = (const float*)d_in[12];
    float* out = (float*)d_out;

    char* p = (char*)d_ws;
    float* agg = (float*)p;    p += 12582912;   // [N][B][H] f32
    float* denom = (float*)p;  p += 49152;
    float* klsum = (float*)p;  p += 4096;
    short* hn = (short*)p;     p += 1572864;
    short* hnT = (short*)p;    p += 1572864;
    short* kml = (short*)p;    p += 4718592;    // [3][4][3072][64]
    short* WTcat = (short*)p;  p += 393216;
    float* biasc = (float*)p;  p += 4096;
    short* WvT = (short*)p;    p += 524288;
    short* aggn = (short*)p;                    // 6291456; total ~27.7 MB

    (void)hipMemsetAsync(agg, 0, 12582912 + 49152 + 4096, stream);  // agg+denom+klsum

    k0_prep<<<113, 256, 0, stream>>>(Wk, Wmu, Wls, bk, bmu, bls, Wv, WTcat, biasc, WvT);
    k1_ln<<<3072, 256, 0, stream>>>(h, gamma, beta, hn);
    k1b_tr<<<192, 256, 0, stream>>>(hn, hnT);
    k2_proj<<<576, 256, 0, stream>>>(hn, WTcat, biasc, kml);
    k3_fused<<<NN / 16 * SP, 256, 0, stream>>>(kml, kml + 4 * NN * HD, kml + 8 * NN * HD,
                                               hnT, eps, diff, agg, denom, klsum);
    k35_norm<<<3072, 256, 0, stream>>>(agg, denom, aggn);
    k4_out<<<192, 256, 0, stream>>>(aggn, WvT, bv, h, klsum, out);
}

// Round 5
// 469.064 us; speedup vs baseline: 1.4825x; 1.1641x over previous
//
#include <hip/hip_runtime.h>
#include <hip/hip_bf16.h>

// BronxLayer fused implementation for MI355X (gfx950).  Round 5.
// N=3072 nodes, H=256 hidden, B=4 heads, HD=64 per-head.
//
// Round-5 changes (r4: k3 313us, atomic tail = 25M f32 atomics = 100MB RMW
// traffic dominated; all MFMA operand loads were 16-txn scatters):
//  - k3: SP=4 partial slices + plain coalesced stores (no agg atomics);
//    k35 reduces 4 slices. ~100MB round-trip (~16us) vs ~250us atomic RMW.
//  - kml stored FRAGMENT-PACKED by k2: [mat][head][ztile][khalf][lane][8],
//    so kh/mu/ls fragment loads are single fully-coalesced 1KB wave loads.
//  - hnT staged in LDS per block (16KB/iter, shared by all 4 waves; was 4x
//    redundant 16-txn scatter), B-frags via conflict-free ds_read_b128.
//  - eps+hnT register-prefetched for iter N+1 during compute of iter N;
//    single-buffer LDS, two short barriers/iter.
//  - memset node dropped: denom/klsum zeroed by extra k0 blocks.

#define NN 3072
#define HH 256
#define NB 4
#define HD 64
constexpr int SP = 4;             // z-splits across workgroups
constexpr int ZCHUNK = NN / SP;   // 768
constexpr int ZT = 32;            // z per iteration
constexpr int NIT = ZCHUNK / ZT;  // 24
constexpr int KMLSZ = 192 * 2 * 64 * 8;  // shorts per (mat,head) = 196608

typedef __attribute__((ext_vector_type(8))) short bf16x8;
typedef __attribute__((ext_vector_type(4))) float f32x4;

static __device__ inline short f2bf(float f) {
    __hip_bfloat16 h = __float2bfloat16(f);
    return __builtin_bit_cast(short, h);
}

// ---------------- k0: weight prep + zero denom/klsum ----------------
// blocks 0..47   : WTcat[cp][yin], cp = mat*256 + (corig&3)*64 + (corig>>2)
// blocks 48..111 : WvT[n][k] = Wv[k][n]
// block  112     : bias permute
// blocks 113..164: zero denom (12288 f32) + klsum (1024 f32), contiguous
__global__ void k0_prep(const float* __restrict__ Wk, const float* __restrict__ Wmu,
                        const float* __restrict__ Wls, const float* __restrict__ bk,
                        const float* __restrict__ bmu, const float* __restrict__ bls,
                        const float* __restrict__ Wv, short* __restrict__ WTcat,
                        float* __restrict__ biascat, short* __restrict__ WvT,
                        float* __restrict__ denom) {
    __shared__ float t[64][65];
    int bx = blockIdx.x;
    if (bx < 48) {
        int mat = bx >> 4;
        int by = (bx >> 2) & 3, bc = bx & 3;
        int y0 = by * 64, c0 = bc * 64;
        const float* W = (mat == 0) ? Wk : (mat == 1 ? Wmu : Wls);
        float scale = (mat == 0) ? 0.125f : 1.f;
        int r = threadIdx.x >> 4, c4 = (threadIdx.x & 15) * 4;
#pragma unroll
        for (int i = 0; i < 4; i++) {
            int yl = r + i * 16;
            float4 v = *(const float4*)(W + (y0 + yl) * 256 + c0 + c4);
            t[yl][c4] = v.x; t[yl][c4 + 1] = v.y; t[yl][c4 + 2] = v.z; t[yl][c4 + 3] = v.w;
        }
        __syncthreads();
#pragma unroll
        for (int i = 0; i < 4; i++) {
            int cl = r + i * 16;
            int corig = c0 + cl;
            int cp = mat * 256 + (corig & 3) * 64 + (corig >> 2);
            short4 v = make_short4(f2bf(t[c4][cl] * scale), f2bf(t[c4 + 1][cl] * scale),
                                   f2bf(t[c4 + 2][cl] * scale), f2bf(t[c4 + 3][cl] * scale));
            *(short4*)(WTcat + cp * 256 + y0 + c4) = v;
        }
        return;
    }
    if (bx < 112) {
        int b = bx - 48;
        int bk2 = b >> 2, bn = b & 3;
        int k0 = bk2 * 64, n0 = bn * 64;
        int r = threadIdx.x >> 4, c4 = (threadIdx.x & 15) * 4;
#pragma unroll
        for (int i = 0; i < 4; i++) {
            int kk = r + i * 16;
            float4 v = *(const float4*)(Wv + (k0 + kk) * 256 + n0 + c4);
            t[kk][c4] = v.x; t[kk][c4 + 1] = v.y; t[kk][c4 + 2] = v.z; t[kk][c4 + 3] = v.w;
        }
        __syncthreads();
#pragma unroll
        for (int i = 0; i < 4; i++) {
            int nn = r + i * 16;
            short4 v = make_short4(f2bf(t[c4][nn]), f2bf(t[c4 + 1][nn]),
                                   f2bf(t[c4 + 2][nn]), f2bf(t[c4 + 3][nn]));
            *(short4*)(WvT + (n0 + nn) * 1024 + k0 + c4) = v;
        }
        return;
    }
    if (bx == 112) {
        int cc = threadIdx.x;
        int corig = (cc & 63) * 4 + (cc >> 6);
        biascat[cc] = bk[corig] * 0.125f;
        biascat[256 + cc] = bmu[corig];
        biascat[512 + cc] = bls[corig];
        return;
    }
    int i = (bx - 113) * 256 + threadIdx.x;
    if (i < 13312) denom[i] = 0.f;   // denom[12288] then klsum[1024], contiguous
}

// ---------------- k1: LayerNorm ----------------
__global__ void k1_ln(const float* __restrict__ h, const float* __restrict__ gamma,
                      const float* __restrict__ beta, short* __restrict__ hn) {
    int row = blockIdx.x, tid = threadIdx.x;
    float v = h[row * 256 + tid];
    float s = v, s2 = v * v;
    for (int off = 32; off; off >>= 1) {
        s += __shfl_xor(s, off);
        s2 += __shfl_xor(s2, off);
    }
    __shared__ float red[8];
    int w = tid >> 6, lane = tid & 63;
    if (!lane) { red[w] = s; red[4 + w] = s2; }
    __syncthreads();
    s = red[0] + red[1] + red[2] + red[3];
    s2 = red[4] + red[5] + red[6] + red[7];
    float mean = s * (1.f / 256.f);
    float var = s2 * (1.f / 256.f) - mean * mean;
    float rs = rsqrtf(var + 1e-5f);
    hn[row * 256 + tid] = f2bf((v - mean) * rs * gamma[tid] + beta[tid]);
}

// ---------------- k1b: transpose hn -> hnT (LDS-tiled) ----------------
__global__ void k1b_tr(const short* __restrict__ hn, short* __restrict__ hnT) {
    __shared__ short t[64][68];
    int bn = blockIdx.x >> 2, bh = blockIdx.x & 3;
    int n0 = bn * 64, h0 = bh * 64;
    int r = threadIdx.x >> 4, c4 = (threadIdx.x & 15) * 4;
#pragma unroll
    for (int i = 0; i < 4; i++) {
        int nn = r + i * 16;
        *(short4*)&t[nn][c4] = *(const short4*)(hn + (n0 + nn) * 256 + h0 + c4);
    }
    __syncthreads();
#pragma unroll
    for (int i = 0; i < 4; i++) {
        int hh = r + i * 16;
        short4 v = make_short4(t[c4][hh], t[c4 + 1][hh], t[c4 + 2][hh], t[c4 + 3][hh]);
        *(short4*)(hnT + (h0 + hh) * NN + n0 + c4) = v;
    }
}

// ---------------- k2: projections (bf16 MFMA), fragment-packed output -----------
// kml packed per (mat,head): idx = ((zt*2 + khalf)*64 + lane)*8 + j
//   element: node z = zt*16 + (lane&15), k = khalf*32 + (lane>>4)*8 + j
__global__ __launch_bounds__(256) void k2_proj(const short* __restrict__ hn,
                                               const short* __restrict__ WTcat,
                                               const float* __restrict__ biascat,
                                               short* __restrict__ kml) {
    int bx = blockIdx.x;
    int mt = bx / 12, nb = bx % 12;
    int m0 = mt * 64, n0 = nb * 64;
    int tid = threadIdx.x, w = tid >> 6, lane = tid & 63, q = lane >> 4, c = lane & 15;
    int mrow = m0 + w * 16;
    f32x4 acc[4] = {{0, 0, 0, 0}, {0, 0, 0, 0}, {0, 0, 0, 0}, {0, 0, 0, 0}};
    for (int k0 = 0; k0 < 256; k0 += 32) {
        bf16x8 af = *(const bf16x8*)(hn + (mrow + c) * 256 + k0 + q * 8);
#pragma unroll
        for (int nt = 0; nt < 4; nt++) {
            bf16x8 bf = *(const bf16x8*)(WTcat + (n0 + nt * 16 + c) * 256 + k0 + q * 8);
            acc[nt] = __builtin_amdgcn_mfma_f32_16x16x32_bf16(af, bf, acc[nt], 0, 0, 0);
        }
    }
#pragma unroll
    for (int nt = 0; nt < 4; nt++) {
        int cp = n0 + nt * 16 + c;
        float bias = biascat[cp];
        int mat = cp >> 8, b = (cp >> 6) & 3, y = cp & 63;
        short* dst = kml + (size_t)(mat * 4 + b) * KMLSZ;
        int kh2 = y >> 5, lq = (y >> 3) & 3, j = y & 7;
        int zt = mt * 4 + w;  // m>>4
#pragma unroll
        for (int r = 0; r < 4; r++) {
            int ml = 4 * q + r;  // m&15
            dst[(((zt * 2 + kh2) * 64) + lq * 16 + ml) * 8 + j] = f2bf(acc[nt][r] + bias);
        }
    }
}

// ---------------- k3: fused attention-like core ----------------
__global__ __launch_bounds__(256) void k3_fused(
    const short* __restrict__ kml, const short* __restrict__ hnT,
    const float* __restrict__ eps, const float* __restrict__ diff,
    float* __restrict__ aggp, float* __restrict__ denom, float* __restrict__ klsum) {
    __shared__ float eps_s[4][32][20];   // [head][z][x] pad20: 2-way reads (free)
    __shared__ float diff_s[32][20];
    __shared__ short hnT_s[16 * 64 * 8]; // [nt][lane][8] fragment-packed, conflict-free
    __shared__ short a_s[4][16][40];     // wave-private
    __shared__ float klred[4];

    const int tid = threadIdx.x;
    const int w = tid >> 6;     // wave == head
    const int lane = tid & 63;
    const int q = lane >> 4;
    const int c = lane & 15;

    const int xt = blockIdx.x >> 2;   // SP==4
    const int sp = blockIdx.x & 3;
    const int x0 = xt * 16;
    const int zbase = sp * ZCHUNK;

    const short* khp = kml + (size_t)(0 * 4 + w) * KMLSZ;
    const short* mup = kml + (size_t)(1 * 4 + w) * KMLSZ;
    const short* lsp = kml + (size_t)(2 * 4 + w) * KMLSZ;

    // kh fragments (B-operand of S^T), coalesced packed loads
    const bf16x8 qf0 = *(const bf16x8*)(khp + ((xt * 2 + 0) * 64 + lane) * 8);
    const bf16x8 qf1 = *(const bf16x8*)(khp + ((xt * 2 + 1) * 64 + lane) * 8);

    f32x4 acc[16];
#pragma unroll
    for (int i = 0; i < 16; i++) acc[i] = (f32x4){0.f, 0.f, 0.f, 0.f};
    float den_acc = 0.f, kl_acc = 0.f;

    int xx[2], zz[2];
#pragma unroll
    for (int i = 0; i < 2; i++) { int p = i * 256 + tid; xx[i] = p >> 5; zz[i] = p & 31; }

    // prologue prefetch: eps/diff + hnT slice for it=0
    f32x4 e_reg[2];
    float d_reg[2];
    bf16x8 hp_reg[4];
#pragma unroll
    for (int i = 0; i < 2; i++) {
        int base = (x0 + xx[i]) * NN + zbase + zz[i];
        e_reg[i] = __builtin_nontemporal_load((const f32x4*)(eps + (size_t)base * 4));
        d_reg[i] = __builtin_nontemporal_load(diff + base);
    }
#pragma unroll
    for (int i = 0; i < 4; i++)
        hp_reg[i] = *(const bf16x8*)(hnT + (size_t)(w * 64 + i * 16 + c) * NN + zbase + q * 8);

    for (int it = 0; it < NIT; ++it) {
        const int z0 = zbase + it * ZT;
        __syncthreads();  // previous compute done reading LDS
        // exclusive LDS-write window: eps/diff + hnT slice from prefetched regs
#pragma unroll
        for (int i = 0; i < 2; i++) {
            eps_s[0][zz[i]][xx[i]] = e_reg[i].x;
            eps_s[1][zz[i]][xx[i]] = e_reg[i].y;
            eps_s[2][zz[i]][xx[i]] = e_reg[i].z;
            eps_s[3][zz[i]][xx[i]] = e_reg[i].w;
            diff_s[zz[i]][xx[i]] = d_reg[i];
        }
#pragma unroll
        for (int i = 0; i < 4; i++)
            *(bf16x8*)(&hnT_s[((w * 4 + i) * 64 + lane) * 8]) = hp_reg[i];
        __syncthreads();

        // prefetch next iteration's eps/diff + hnT
        if (it + 1 < NIT) {
            const int z1 = z0 + ZT;
#pragma unroll
            for (int i = 0; i < 2; i++) {
                int base = (x0 + xx[i]) * NN + z1 + zz[i];
                e_reg[i] = __builtin_nontemporal_load((const f32x4*)(eps + (size_t)base * 4));
                d_reg[i] = __builtin_nontemporal_load(diff + base);
            }
#pragma unroll
            for (int i = 0; i < 4; i++)
                hp_reg[i] = *(const bf16x8*)(hnT + (size_t)(w * 64 + i * 16 + c) * NN + z1 + q * 8);
        }

        // S^T = mu/ls @ kh^T: D[m=z][n=x]; packed coalesced A-frag loads
        const int zt0 = (zbase >> 4) + it * 2;
        f32x4 smu[2], sls[2];
#pragma unroll
        for (int t = 0; t < 2; t++) {
            bf16x8 a0 = *(const bf16x8*)(mup + (((zt0 + t) * 2 + 0) * 64 + lane) * 8);
            bf16x8 a1 = *(const bf16x8*)(mup + (((zt0 + t) * 2 + 1) * 64 + lane) * 8);
            f32x4 z4 = (f32x4){0.f, 0.f, 0.f, 0.f};
            z4 = __builtin_amdgcn_mfma_f32_16x16x32_bf16(a0, qf0, z4, 0, 0, 0);
            z4 = __builtin_amdgcn_mfma_f32_16x16x32_bf16(a1, qf1, z4, 0, 0, 0);
            smu[t] = z4;
            bf16x8 b0 = *(const bf16x8*)(lsp + (((zt0 + t) * 2 + 0) * 64 + lane) * 8);
            bf16x8 b1 = *(const bf16x8*)(lsp + (((zt0 + t) * 2 + 1) * 64 + lane) * 8);
            f32x4 y4 = (f32x4){0.f, 0.f, 0.f, 0.f};
            y4 = __builtin_amdgcn_mfma_f32_16x16x32_bf16(b0, qf0, y4, 0, 0, 0);
            y4 = __builtin_amdgcn_mfma_f32_16x16x32_bf16(b1, qf1, y4, 0, 0, 0);
            sls[t] = y4;
        }

        // elementwise: x = x0 + c, z = z0 + 16t + 4q + r
#pragma unroll
        for (int t = 0; t < 2; t++) {
            short pk[4];
#pragma unroll
            for (int r = 0; r < 4; r++) {
                int zl = t * 16 + 4 * q + r;
                float mu = smu[t][r];
                float ls = sls[t][r];
                float e = eps_s[w][zl][c];
                float d = diff_s[zl][c];
                float ex = __expf(-fabsf(ls));
                float sg = fmaxf(ls, 0.f) + __logf(1.f + ex);
                float kle = -__logf(sg) + 0.5f * (sg * sg + mu * mu) - 0.5f;
                float sgn = (d > 0.f) ? 1.f : ((d < 0.f) ? -1.f : 0.f);
                kl_acc += sgn * kle;
                float a = __expf(mu + sg * e) * d;
                den_acc += fabsf(a);
                pk[r] = f2bf(a);
            }
            *reinterpret_cast<short4*>(&a_s[w][c][t * 16 + 4 * q]) =
                make_short4(pk[0], pk[1], pk[2], pk[3]);
        }
        // a_s wave-private; same-wave DS ordering -> no barrier needed here
        bf16x8 af = *(const bf16x8*)(&a_s[w][c][q * 8]);
#pragma unroll
        for (int nt = 0; nt < 16; nt++) {
            bf16x8 bfr = *(const bf16x8*)(&hnT_s[(nt * 64 + lane) * 8]);
            acc[nt] = __builtin_amdgcn_mfma_f32_16x16x32_bf16(af, bfr, acc[nt], 0, 0, 0);
        }
    }

    // denominator: lane's elements all at x = x0 + c; reduce across quads
    den_acc += __shfl_down(den_acc, 32);
    den_acc += __shfl_down(den_acc, 16);
    if (q == 0) atomicAdd(&denom[(x0 + c) * NB + w], den_acc);
    // kl: wave reduce, then block reduce, 1 atomic per block
    for (int off = 32; off; off >>= 1) kl_acc += __shfl_xor(kl_acc, off);
    if (lane == 0) klred[w] = kl_acc;
    __syncthreads();
    if (tid == 0) atomicAdd(klsum, klred[0] + klred[1] + klred[2] + klred[3]);

    // agg partials: plain coalesced-segment stores into private sp-slice
    float* dst = aggp + (size_t)sp * (NN * NB * HH);
#pragma unroll
    for (int nt = 0; nt < 16; nt++)
#pragma unroll
        for (int r = 0; r < 4; r++)
            dst[((size_t)(x0 + 4 * q + r) * NB + w) * HH + nt * 16 + c] = acc[nt][r];
}

// ---------------- k35: reduce 4 partials + normalize -> bf16 ----------------
__global__ void k35_norm(const float* __restrict__ aggp, const float* __restrict__ denom,
                         short* __restrict__ aggn) {
    int x = blockIdx.x, tid = threadIdx.x;
    int b = tid >> 6;
    int h4 = (tid & 63) * 4;
    size_t base = ((size_t)x * 4 + b) * 256 + h4;
    float4 s = {0.f, 0.f, 0.f, 0.f};
#pragma unroll
    for (int sp = 0; sp < SP; sp++) {
        float4 v = *(const float4*)(aggp + (size_t)sp * (NN * 4 * 256) + base);
        s.x += v.x; s.y += v.y; s.z += v.z; s.w += v.w;
    }
    float r = 1.f / fmaxf(denom[x * 4 + b], 1e-12f);
    short4 o = make_short4(f2bf(s.x * r), f2bf(s.y * r), f2bf(s.z * r), f2bf(s.w * r));
    *(short4*)(aggn + base) = o;
}

// ---------------- k4: fc_v + elu + residual + kl ----------------
__global__ __launch_bounds__(256) void k4_out(const short* __restrict__ aggn,
                                              const short* __restrict__ WvT,
                                              const float* __restrict__ bv,
                                              const float* __restrict__ h,
                                              const float* __restrict__ klsum,
                                              float* __restrict__ out) {
    int bx = blockIdx.x;
    int mt = bx >> 2, nb = bx & 3;
    int m0 = mt * 64, n0 = nb * 64;
    int tid = threadIdx.x, w = tid >> 6, lane = tid & 63, q = lane >> 4, c = lane & 15;
    int mrow = m0 + w * 16;
    f32x4 acc[4] = {{0, 0, 0, 0}, {0, 0, 0, 0}, {0, 0, 0, 0}, {0, 0, 0, 0}};
    for (int k0 = 0; k0 < 1024; k0 += 32) {
        bf16x8 af = *(const bf16x8*)(aggn + (mrow + c) * 1024 + k0 + q * 8);
#pragma unroll
        for (int nt = 0; nt < 4; nt++) {
            bf16x8 bf = *(const bf16x8*)(WvT + (n0 + nt * 16 + c) * 1024 + k0 + q * 8);
            acc[nt] = __builtin_amdgcn_mfma_f32_16x16x32_bf16(af, bf, acc[nt], 0, 0, 0);
        }
    }
#pragma unroll
    for (int nt = 0; nt < 4; nt++) {
        int col = n0 + nt * 16 + c;
        float bias = bv[col];
#pragma unroll
        for (int r = 0; r < 4; r++) {
            int row = mrow + 4 * q + r;
            float v = acc[nt][r] + bias;
            v = (v > 0.f) ? v : (__expf(v) - 1.f);  // elu
            out[row * 256 + col] = v + h[row * 256 + col];
        }
    }
    if (bx == 0 && tid == 0) out[786432] = klsum[0] * (1.0f / 9437184.0f);
}

extern "C" void kernel_launch(void* const* d_in, const int* in_sizes, int n_in,
                              void* d_out, int out_size, void* d_ws, size_t ws_size,
                              hipStream_t stream) {
    const float* h = (const float*)d_in[0];
    const float* gamma = (const float*)d_in[1];
    const float* beta = (const float*)d_in[2];
    const float* Wk = (const float*)d_in[3];
    const float* bk = (const float*)d_in[4];
    const float* Wmu = (const float*)d_in[5];
    const float* bmu = (const float*)d_in[6];
    const float* Wls = (const float*)d_in[7];
    const float* bls = (const float*)d_in[8];
    const float* Wv = (const float*)d_in[9];
    const float* bv = (const float*)d_in[10];
    const float* diff = (const float*)d_in[11];
    const float* eps = (const float*)d_in[12];
    float* out = (float*)d_out;

    char* p = (char*)d_ws;
    float* aggp = (float*)p;   p += (size_t)SP * 12582912;  // 50.3 MB partial slices
    float* denom = (float*)p;  p += 49152;                  // + klsum contiguous
    float* klsum = (float*)p;  p += 4096;
    short* hn = (short*)p;     p += 1572864;
    short* hnT = (short*)p;    p += 1572864;
    short* kml = (short*)p;    p += 4718592;                // fragment-packed
    short* WTcat = (short*)p;  p += 393216;
    float* biasc = (float*)p;  p += 4096;
    short* WvT = (short*)p;    p += 524288;
    short* aggn = (short*)p;                                // 6291456; total ~65.4 MB

    k0_prep<<<165, 256, 0, stream>>>(Wk, Wmu, Wls, bk, bmu, bls, Wv, WTcat, biasc, WvT,
                                     denom);
    k1_ln<<<3072, 256, 0, stream>>>(h, gamma, beta, hn);
    k1b_tr<<<192, 256, 0, stream>>>(hn, hnT);
    k2_proj<<<576, 256, 0, stream>>>(hn, WTcat, biasc, kml);
    k3_fused<<<192 * SP, 256, 0, stream>>>(kml, hnT, eps, diff, aggp, denom, klsum);
    k35_norm<<<3072, 256, 0, stream>>>(aggp, denom, aggn);
    k4_out<<<192, 256, 0, stream>>>(aggn, WvT, bv, h, klsum, out);
}